// Round 1
// baseline (779.775 us; speedup 1.0000x reference)
//
#include <hip/hip_runtime.h>

#define NN 50000
#define EE 600000
#define DF 128

// ---------------- degree: deg[row[e]] += w[e] ----------------
__global__ void deg_kernel(const int* __restrict__ row, const float* __restrict__ w,
                           float* __restrict__ deg, int E) {
    int e = blockIdx.x * blockDim.x + threadIdx.x;
    if (e < E) atomicAdd(&deg[row[e]], w[e]);
}

// ---------------- norm[e] = dis[row]*w*dis[col] ----------------
__global__ void norm_kernel(const int* __restrict__ row, const int* __restrict__ col,
                            const float* __restrict__ w, const float* __restrict__ deg,
                            float* __restrict__ norm, int E) {
    int e = blockIdx.x * blockDim.x + threadIdx.x;
    if (e < E) {
        float dr = deg[row[e]];
        float dc = deg[col[e]];
        norm[e] = rsqrtf(dr) * w[e] * rsqrtf(dc);
    }
}

// ---------------- H = (relu?)X @ W^T + b ----------------
// one thread per output column; W row held in 128 VGPRs; x row broadcast via LDS.
#define ROWS_PER_BLOCK 32
template <bool RELU_IN>
__global__ __launch_bounds__(128) void gemm128_kernel(
    const float* __restrict__ X, const float* __restrict__ W,
    const float* __restrict__ b, float* __restrict__ H, int nrows)
{
    __shared__ float xs[DF];
    const int t = threadIdx.x;            // output column 0..127
    float wreg[DF];
    const float4* wr = (const float4*)(W + t * DF);
#pragma unroll
    for (int j = 0; j < DF / 4; ++j) {
        float4 v = wr[j];
        wreg[4 * j + 0] = v.x; wreg[4 * j + 1] = v.y;
        wreg[4 * j + 2] = v.z; wreg[4 * j + 3] = v.w;
    }
    const float bias = b[t];
    const int row0 = blockIdx.x * ROWS_PER_BLOCK;
    for (int r = 0; r < ROWS_PER_BLOCK; ++r) {
        const int n = row0 + r;
        if (n >= nrows) break;            // uniform across block
        float xv = X[n * DF + t];
        if (RELU_IN) xv = fmaxf(xv, 0.0f);
        __syncthreads();                  // protect xs readers from prev iter
        xs[t] = xv;
        __syncthreads();
        float acc = bias;
        const float4* xs4 = (const float4*)xs;
#pragma unroll
        for (int j = 0; j < DF / 4; ++j) {
            float4 x4 = xs4[j];           // ds_read_b128, broadcast (same addr)
            acc = fmaf(x4.x, wreg[4 * j + 0], acc);
            acc = fmaf(x4.y, wreg[4 * j + 1], acc);
            acc = fmaf(x4.z, wreg[4 * j + 2], acc);
            acc = fmaf(x4.w, wreg[4 * j + 3], acc);
        }
        H[n * DF + t] = acc;
    }
}

// ---------------- out[col[e]] += norm[e] * H[row[e]] ----------------
__global__ void scatter_kernel(const float* __restrict__ H, const float* __restrict__ norm,
                               const int* __restrict__ row, const int* __restrict__ col,
                               float* __restrict__ out, int E)
{
    const long long gid = (long long)blockIdx.x * blockDim.x + threadIdx.x;
    const int e = (int)(gid >> 7);
    const int f = (int)(gid & 127);
    if (e >= E) return;
    const int   r = row[e];
    const int   c = col[e];
    const float v = norm[e] * H[(long long)r * DF + f];
    atomicAdd(&out[(long long)c * DF + f], v);
}

extern "C" void kernel_launch(void* const* d_in, const int* in_sizes, int n_in,
                              void* d_out, int out_size, void* d_ws, size_t ws_size,
                              hipStream_t stream) {
    const float* x  = (const float*)d_in[0];
    const int*   ei = (const int*)d_in[1];
    const float* ew = (const float*)d_in[2];
    const float* W1 = (const float*)d_in[3];
    const float* b1 = (const float*)d_in[4];
    const float* W2 = (const float*)d_in[5];
    const float* b2 = (const float*)d_in[6];
    float* out = (float*)d_out;

    const int E = in_sizes[2];        // 600000
    const int N = in_sizes[0] / DF;   // 50000
    const int* row = ei;
    const int* col = ei + E;

    // workspace layout (bytes, 512-aligned)
    char* ws = (char*)d_ws;
    size_t off = 0;
    auto alloc = [&](size_t bytes) { char* p = ws + off; off = (off + bytes + 511) & ~(size_t)511; return p; };
    float* deg  = (float*)alloc((size_t)N * 4);
    float* norm = (float*)alloc((size_t)E * 4);
    float* h1   = (float*)alloc((size_t)N * DF * 4);   // layer1 linear out; reused for layer2 linear out
    float* agg1 = (float*)alloc((size_t)N * DF * 4);   // layer1 aggregate (pre-relu)
    (void)ws_size;

    // zero accumulators (ws/out are poisoned 0xAA before every call)
    hipMemsetAsync(deg, 0, (size_t)N * 4, stream);
    hipMemsetAsync(agg1, 0, (size_t)N * DF * 4, stream);
    hipMemsetAsync(out, 0, (size_t)N * DF * 4, stream);

    const int TB = 256;
    deg_kernel<<<(E + TB - 1) / TB, TB, 0, stream>>>(row, ew, deg, E);
    norm_kernel<<<(E + TB - 1) / TB, TB, 0, stream>>>(row, col, ew, deg, norm, E);

    const int gemm_blocks = (N + ROWS_PER_BLOCK - 1) / ROWS_PER_BLOCK;
    gemm128_kernel<false><<<gemm_blocks, 128, 0, stream>>>(x, W1, b1, h1, N);

    const long long sc_threads = (long long)E * DF;
    const int sc_blocks = (int)((sc_threads + TB - 1) / TB);
    scatter_kernel<<<sc_blocks, TB, 0, stream>>>(h1, norm, row, col, agg1, E);

    gemm128_kernel<true><<<gemm_blocks, 128, 0, stream>>>(agg1, W2, b2, h1, N);
    scatter_kernel<<<sc_blocks, TB, 0, stream>>>(h1, norm, row, col, out, E);
}